// Round 1
// baseline (211.427 us; speedup 1.0000x reference)
//
#include <hip/hip_runtime.h>
#include <hip/hip_fp16.h>

// probs = |U^{⊗8} f|^2 / ||f||^2 for a 24-qubit state, U = 8x8 complex gate.
// Plan:
//  K0 : block partial sums of f^2            -> d_out[0:2048] (scratch, pre-pass1)
//  K0b: reduce partials -> 1/sum(f^2)        -> d_ws[0]   (only 4 bytes of ws used)
//  K1 : gates on axes 3..7 (low 15 bits). 512 blocks x 1024 thr, 32768-complex
//       contiguous tile in 128KB fp16 LDS (half2 re,im), 5 in-place stages,
//       last stage streams half2 intermediate into d_out (natural layout).
//  K2 : gates on axes 0..2 (high 9 bits). 2048 blocks x 512 thr, tile =
//       512 h x 16 consecutive lows (64KB fp32 LDS), 3 stages, then
//       probs = (re^2+im^2)*invn2 -> d_out (each block's region is private:
//       reads and writes of d_out are the same disjoint 16-low slice).
// All LDS layouts XOR-swizzled so every stage access is at the bank minimum.

typedef float v2f __attribute__((ext_vector_type(2)));

#define SWZ1(e) ((e) ^ (((e) >> 6) & 7) ^ ((((e) >> 9) & 3) << 3))
#define SWZ2(e) ((e) ^ ((((e) >> 4) & 7) << 1))

__device__ __forceinline__ constexpr int tj1(int stage, int j) {
  return stage == 7 ? j
       : stage == 6 ? (j << 3)
       : stage == 5 ? ((j << 6) ^ j)
       : stage == 4 ? ((j << 9) ^ ((j & 3) << 3))
       :              (j << 12);
}
__device__ __forceinline__ constexpr int tj2(int stage, int j) {
  return stage == 2 ? ((j << 4) ^ (j << 1))
       : stage == 1 ? (j << 7)
       :              (j << 10);
}

__device__ __forceinline__ v2f mkv(float a, float b) { v2f r; r.x = a; r.y = b; return r; }

// ---------------- K0: partial sum of squares ----------------
__global__ __launch_bounds__(256) void k_sumsq(const float* __restrict__ f,
                                               float* __restrict__ partial) {
  const int t = threadIdx.x;
  const float4* f4 = reinterpret_cast<const float4*>(f) + ((size_t)blockIdx.x << 11);
  float s = 0.f;
#pragma unroll
  for (int i = 0; i < 8; ++i) {
    float4 v = f4[(i << 8) + t];
    s += v.x * v.x + v.y * v.y + v.z * v.z + v.w * v.w;
  }
#pragma unroll
  for (int off = 32; off > 0; off >>= 1) s += __shfl_down(s, off, 64);
  __shared__ float red[4];
  if ((t & 63) == 0) red[t >> 6] = s;
  __syncthreads();
  if (t == 0) partial[blockIdx.x] = (red[0] + red[1]) + (red[2] + red[3]);
}

// ---------------- K0b: finish reduction -> 1/sum ----------------
__global__ __launch_bounds__(256) void k_finish(const float* __restrict__ partial,
                                                float* __restrict__ invn2) {
  const int t = threadIdx.x;
  float s = 0.f;
#pragma unroll
  for (int i = 0; i < 8; ++i) s += partial[(i << 8) + t];
#pragma unroll
  for (int off = 32; off > 0; off >>= 1) s += __shfl_down(s, off, 64);
  __shared__ float red[4];
  if ((t & 63) == 0) red[t >> 6] = s;
  __syncthreads();
  if (t == 0) invn2[0] = 1.0f / ((red[0] + red[1]) + (red[2] + red[3]));
}

// ---------------- K1: axes 3..7 ----------------
// element index e (15b): i3=e[14:12] i4=e[11:9] i5=e[8:6] i6=e[5:3] i7=e[2:0]
template <int STAGE>
__device__ __forceinline__ void stage1_c(__half2* tile, const float* __restrict__ gr,
                                         const float* __restrict__ gi, int eb0, int eb1) {
  const int pb0 = SWZ1(eb0), pb1 = SWZ1(eb1);
  v2f a0[8], a1[8];
#pragma unroll
  for (int i = 0; i < 8; ++i) { a0[i] = mkv(0.f, 0.f); a1[i] = mkv(0.f, 0.f); }
#pragma unroll
  for (int j = 0; j < 8; ++j) {
    const float2 v0 = __half22float2(tile[pb0 ^ tj1(STAGE, j)]);
    const float2 v1 = __half22float2(tile[pb1 ^ tj1(STAGE, j)]);
    const v2f p0 = mkv(v0.x, v0.y), q0 = mkv(-v0.y, v0.x);
    const v2f p1 = mkv(v1.x, v1.y), q1 = mkv(-v1.y, v1.x);
#pragma unroll
    for (int i = 0; i < 8; ++i) {
      const float gre = gr[i * 8 + j], gim = gi[i * 8 + j];
      a0[i] = __builtin_elementwise_fma(mkv(gre, gre), p0, a0[i]);
      a0[i] = __builtin_elementwise_fma(mkv(gim, gim), q0, a0[i]);
      a1[i] = __builtin_elementwise_fma(mkv(gre, gre), p1, a1[i]);
      a1[i] = __builtin_elementwise_fma(mkv(gim, gim), q1, a1[i]);
    }
  }
#pragma unroll
  for (int i = 0; i < 8; ++i) {
    tile[pb0 ^ tj1(STAGE, i)] = __float22half2_rn(make_float2(a0[i].x, a0[i].y));
    tile[pb1 ^ tj1(STAGE, i)] = __float22half2_rn(make_float2(a1[i].x, a1[i].y));
  }
}

__global__ __launch_bounds__(1024) void k_pass1(const float* __restrict__ f,
                                                const float* __restrict__ gr,
                                                const float* __restrict__ gi,
                                                __half2* __restrict__ st) {
  __shared__ __align__(16) __half2 tile[32768];  // 128 KB
  const int t = threadIdx.x;
  const int l = t & 63, w = t >> 6;                 // lane(6b), wave(4b)
  const int l20 = l & 7, l43 = (l >> 3) & 3, l5 = l >> 5;
  const int w20 = w & 7, w3 = w >> 3;
  const int A = (l5 << 2) | l43;                    // 3b {l5,l43}
  const size_t blk = blockIdx.x;

  // fill: coalesced float4 feature loads -> half2(re,0) at swizzled LDS slots.
  // swizzle only permutes bits[1:0] by d=l[5:4] within each aligned 4-block.
  {
    const float4* fin = reinterpret_cast<const float4*>(f) + (blk << 13);
    const int d = (l >> 4) & 3;
    const bool b0 = (d & 1) != 0, b1 = (d & 2) != 0;
#pragma unroll
    for (int k = 0; k < 8; ++k) {
      const float4 v = fin[(k << 10) + t];
      const int e0 = (k << 12) | (t << 2);
      const int pblk = SWZ1(e0) & ~3;
      const uint x0 = (uint)__half_as_ushort(__float2half_rn(v.x));
      const uint x1 = (uint)__half_as_ushort(__float2half_rn(v.y));
      const uint x2 = (uint)__half_as_ushort(__float2half_rn(v.z));
      const uint x3 = (uint)__half_as_ushort(__float2half_rn(v.w));
      const uint y0 = b0 ? x1 : x0, y1 = b0 ? x0 : x1;
      const uint y2 = b0 ? x3 : x2, y3 = b0 ? x2 : x3;
      const uint4 W = make_uint4(b1 ? y2 : y0, b1 ? y3 : y1, b1 ? y0 : y2, b1 ? y1 : y3);
      *reinterpret_cast<uint4*>(reinterpret_cast<uint*>(tile) + pblk) = W;
    }
  }
  __syncthreads();

  // stage 7 (axis 7, real input -> 1 packed FMA per (i,j,group))
#pragma unroll
  for (int cp = 0; cp < 2; ++cp) {
    const int Wc0 = (w3 << 2) | (cp << 1), Wc1 = Wc0 | 1;
    const int eb0 = (w20 << 12) | (A << 9) | (l20 << 6) | (Wc0 << 3);
    const int eb1 = (w20 << 12) | (A << 9) | (l20 << 6) | (Wc1 << 3);
    const int pb0 = SWZ1(eb0), pb1 = SWZ1(eb1);
    v2f a0[8], a1[8];
#pragma unroll
    for (int i = 0; i < 8; ++i) { a0[i] = mkv(0.f, 0.f); a1[i] = mkv(0.f, 0.f); }
#pragma unroll
    for (int j = 0; j < 8; ++j) {
      const float vr0 = __half22float2(tile[pb0 ^ j]).x;
      const float vr1 = __half22float2(tile[pb1 ^ j]).x;
#pragma unroll
      for (int i = 0; i < 8; ++i) {
        const v2f g = mkv(gr[i * 8 + j], gi[i * 8 + j]);
        a0[i] = __builtin_elementwise_fma(g, mkv(vr0, vr0), a0[i]);
        a1[i] = __builtin_elementwise_fma(g, mkv(vr1, vr1), a1[i]);
      }
    }
#pragma unroll
    for (int i = 0; i < 8; ++i) {
      tile[pb0 ^ i] = __float22half2_rn(make_float2(a0[i].x, a0[i].y));
      tile[pb1 ^ i] = __float22half2_rn(make_float2(a1[i].x, a1[i].y));
    }
  }
  __syncthreads();

  // stage 6
#pragma unroll
  for (int cp = 0; cp < 2; ++cp) {
    const int Wc0 = (w3 << 2) | (cp << 1), Wc1 = Wc0 | 1;
    stage1_c<6>(tile, gr, gi,
                (w20 << 12) | (A << 9) | (Wc0 << 6) | l20,
                (w20 << 12) | (A << 9) | (Wc1 << 6) | l20);
  }
  __syncthreads();
  // stage 5
#pragma unroll
  for (int cp = 0; cp < 2; ++cp) {
    const int Wc0 = (w3 << 2) | (cp << 1), Wc1 = Wc0 | 1;
    stage1_c<5>(tile, gr, gi,
                (w20 << 12) | (A << 9) | (Wc0 << 3) | l20,
                (w20 << 12) | (A << 9) | (Wc1 << 3) | l20);
  }
  __syncthreads();
  // stage 4
#pragma unroll
  for (int cp = 0; cp < 2; ++cp) {
    const int Wc0 = (w3 << 2) | (cp << 1), Wc1 = Wc0 | 1;
    stage1_c<4>(tile, gr, gi,
                (w20 << 12) | (Wc0 << 6) | (A << 3) | l20,
                (w20 << 12) | (Wc1 << 6) | (A << 3) | l20);
  }
  __syncthreads();

  // stage 3: compute and stream straight to global (coalesced 64-consecutive half2)
#pragma unroll
  for (int cp = 0; cp < 2; ++cp) {
    const int Wc0 = (w3 << 2) | (cp << 1), Wc1 = Wc0 | 1;
    const int eb0 = (w20 << 9) | (Wc0 << 6) | (A << 3) | l20;
    const int eb1 = (w20 << 9) | (Wc1 << 6) | (A << 3) | l20;
    const int pb0 = SWZ1(eb0), pb1 = SWZ1(eb1);
    v2f a0[8], a1[8];
#pragma unroll
    for (int i = 0; i < 8; ++i) { a0[i] = mkv(0.f, 0.f); a1[i] = mkv(0.f, 0.f); }
#pragma unroll
    for (int j = 0; j < 8; ++j) {
      const float2 v0 = __half22float2(tile[pb0 ^ (j << 12)]);
      const float2 v1 = __half22float2(tile[pb1 ^ (j << 12)]);
      const v2f p0 = mkv(v0.x, v0.y), q0 = mkv(-v0.y, v0.x);
      const v2f p1 = mkv(v1.x, v1.y), q1 = mkv(-v1.y, v1.x);
#pragma unroll
      for (int i = 0; i < 8; ++i) {
        const float gre = gr[i * 8 + j], gim = gi[i * 8 + j];
        a0[i] = __builtin_elementwise_fma(mkv(gre, gre), p0, a0[i]);
        a0[i] = __builtin_elementwise_fma(mkv(gim, gim), q0, a0[i]);
        a1[i] = __builtin_elementwise_fma(mkv(gre, gre), p1, a1[i]);
        a1[i] = __builtin_elementwise_fma(mkv(gim, gim), q1, a1[i]);
      }
    }
    const size_t ob = blk << 15;
#pragma unroll
    for (int i = 0; i < 8; ++i) {
      st[ob + (size_t)((i << 12) | eb0)] = __float22half2_rn(make_float2(a0[i].x, a0[i].y));
      st[ob + (size_t)((i << 12) | eb1)] = __float22half2_rn(make_float2(a1[i].x, a1[i].y));
    }
  }
}

// ---------------- K2: axes 0..2 + |.|^2 ----------------
// element index e (13b): i0=e[12:10] i1=e[9:7] i2=e[6:4] lo=e[3:0]
template <int STAGE>
__device__ __forceinline__ void stage2_c(float2* tile, const float* __restrict__ gr,
                                         const float* __restrict__ gi, int eb0, int eb1) {
  const int pb0 = SWZ2(eb0), pb1 = SWZ2(eb1);
  v2f a0[8], a1[8];
#pragma unroll
  for (int i = 0; i < 8; ++i) { a0[i] = mkv(0.f, 0.f); a1[i] = mkv(0.f, 0.f); }
#pragma unroll
  for (int j = 0; j < 8; ++j) {
    const float2 v0 = tile[pb0 ^ tj2(STAGE, j)];
    const float2 v1 = tile[pb1 ^ tj2(STAGE, j)];
    const v2f p0 = mkv(v0.x, v0.y), q0 = mkv(-v0.y, v0.x);
    const v2f p1 = mkv(v1.x, v1.y), q1 = mkv(-v1.y, v1.x);
#pragma unroll
    for (int i = 0; i < 8; ++i) {
      const float gre = gr[i * 8 + j], gim = gi[i * 8 + j];
      a0[i] = __builtin_elementwise_fma(mkv(gre, gre), p0, a0[i]);
      a0[i] = __builtin_elementwise_fma(mkv(gim, gim), q0, a0[i]);
      a1[i] = __builtin_elementwise_fma(mkv(gre, gre), p1, a1[i]);
      a1[i] = __builtin_elementwise_fma(mkv(gim, gim), q1, a1[i]);
    }
  }
#pragma unroll
  for (int i = 0; i < 8; ++i) {
    tile[pb0 ^ tj2(STAGE, i)] = make_float2(a0[i].x, a0[i].y);
    tile[pb1 ^ tj2(STAGE, i)] = make_float2(a1[i].x, a1[i].y);
  }
}

__global__ __launch_bounds__(512) void k_pass2(const uint4* gp, const float* __restrict__ gr,
                                               const float* __restrict__ gi,
                                               const float* __restrict__ invn2, float* out) {
  __shared__ __align__(16) float2 tile[8192];  // 64 KB
  const int t = threadIdx.x;
  const int l = t & 63, w = t >> 6;            // lane(6b), wave(3b)
  const int l15 = l & 15, l54 = l >> 4;
  const size_t blk = blockIdx.x;               // lows [blk*16, blk*16+16)

  // fill: 64B row (16 half2) per h, fully line-covered loads; pairs of b128 LDS writes
#pragma unroll
  for (int i = 0; i < 4; ++i) {
    const int cidx = (i << 9) + t;
    const int h = cidx >> 2, q = cidx & 3;
    const uint4 raw = gp[(size_t)h * 8192 + (blk << 2) + q];
    const int e0 = (h << 4) | (q << 2);
    const int p0 = SWZ2(e0);
    const float2 f0 = __half22float2(*reinterpret_cast<const __half2*>(&raw.x));
    const float2 f1 = __half22float2(*reinterpret_cast<const __half2*>(&raw.y));
    const float2 f2 = __half22float2(*reinterpret_cast<const __half2*>(&raw.z));
    const float2 f3 = __half22float2(*reinterpret_cast<const __half2*>(&raw.w));
    float4* t4 = reinterpret_cast<float4*>(tile);
    t4[p0 >> 1] = make_float4(f0.x, f0.y, f1.x, f1.y);
    t4[(p0 >> 1) ^ 1] = make_float4(f2.x, f2.y, f3.x, f3.y);
  }
  __syncthreads();

  // stage 2 (axis 2)
  stage2_c<2>(tile, gr, gi,
              (w << 10) | (((l54 << 1) | 0) << 7) | l15,
              (w << 10) | (((l54 << 1) | 1) << 7) | l15);
  __syncthreads();
  // stage 1 (axis 1)
  stage2_c<1>(tile, gr, gi,
              (w << 10) | (((0 << 2) | l54) << 4) | l15,
              (w << 10) | (((1 << 2) | l54) << 4) | l15);
  __syncthreads();
  // stage 0 (axis 0)
  stage2_c<0>(tile, gr, gi,
              (w << 7) | (((0 << 2) | l54) << 4) | l15,
              (w << 7) | (((1 << 2) | l54) << 4) | l15);
  __syncthreads();

  // final: probs, 4 full 64B lines per store instruction
  const float s = invn2[0];
#pragma unroll
  for (int r = 0; r < 16; ++r) {
    const int h = (r << 5) | (w << 2) | l54;
    const float2 a = tile[SWZ2((h << 4) | l15)];
    out[(size_t)h * 32768 + (blk << 4) + l15] = (a.x * a.x + a.y * a.y) * s;
  }
}

extern "C" void kernel_launch(void* const* d_in, const int* in_sizes, int n_in,
                              void* d_out, int out_size, void* d_ws, size_t ws_size,
                              hipStream_t stream) {
  (void)in_sizes; (void)n_in; (void)out_size; (void)ws_size;
  const float* feature = (const float*)d_in[0];
  const float* gr = (const float*)d_in[1];
  const float* gi = (const float*)d_in[2];
  float* out = (float*)d_out;
  float* invn2 = (float*)d_ws;   // only 4 bytes of workspace used

  // partials live in the front of d_out; K1 overwrites d_out afterwards.
  k_sumsq<<<dim3(2048), dim3(256), 0, stream>>>(feature, out);
  k_finish<<<dim3(1), dim3(256), 0, stream>>>(out, invn2);
  k_pass1<<<dim3(512), dim3(1024), 0, stream>>>(feature, gr, gi, (__half2*)d_out);
  k_pass2<<<dim3(2048), dim3(512), 0, stream>>>((const uint4*)d_out, gr, gi, invn2, out);
}

// Round 2
// 159.876 us; speedup vs baseline: 1.3224x; 1.3224x over previous
//
#include <hip/hip_runtime.h>
#include <hip/hip_fp16.h>

// probs = |U^{⊗8} f|^2 / ||f||^2 for a 24-qubit state, U = 8x8 complex gate.
//  K0 : block partial sums of f^2            -> d_out[0:2048] (scratch)
//  K0b: reduce -> 1/sum(f^2) at ws+0; build packed gate table P[(j,i)] =
//       (Gr[i][j], Gi[i][j]) at ws+64 (float2[64], read as u64 sgpr pairs).
//  K1 : gates on axes 3..7 (low 15 bits), 128KB fp16 LDS tile, 5 stages.
//  K2 : gates on axes 0..2 (high 9 bits), 64KB fp32 LDS tile, 3 stages + |.|^2.
// Inner math: complex MAC = 2x v_pk_fma_f32 (op_sel broadcast + neg_lo), gate
// operand from SGPR pair -> no v_mov traffic. Layouts identical to r1 kernel.

typedef float v2f __attribute__((ext_vector_type(2)));
typedef unsigned long long u64;

#define SWZ1(e) ((e) ^ (((e) >> 6) & 7) ^ ((((e) >> 9) & 3) << 3))
#define SWZ2(e) ((e) ^ ((((e) >> 4) & 7) << 1))

__device__ __forceinline__ constexpr int tj1(int stage, int j) {
  return stage == 7 ? j
       : stage == 6 ? (j << 3)
       : stage == 5 ? ((j << 6) ^ j)
       : stage == 4 ? ((j << 9) ^ ((j & 3) << 3))
       :              (j << 12);
}
__device__ __forceinline__ constexpr int tj2(int stage, int j) {
  return stage == 2 ? ((j << 4) ^ (j << 1))
       : stage == 1 ? (j << 7)
       :              (j << 10);
}

__device__ __forceinline__ v2f mkv(float a, float b) { v2f r; r.x = a; r.y = b; return r; }

// acc.(re,im) += (gr,gi) * (v.re + i*v.im); g = (gr,gi) as 2xf32 in an SGPR pair.
// fma1: lo += gr*re         , hi += gi*re
// fma2: lo += -gi*im        , hi += gr*im
__device__ __forceinline__ void cmac(v2f& acc, const u64 g, const v2f v) {
  asm("v_pk_fma_f32 %0, %1, %2, %0 op_sel:[0,0,0] op_sel_hi:[1,0,1]\n\t"
      "v_pk_fma_f32 %0, %1, %2, %0 op_sel:[1,1,0] op_sel_hi:[0,1,1] neg_lo:[1,0,0]"
      : "+v"(acc)
      : "s"(g), "v"(v));
}
// acc += (gr,gi) * vv.lo   (real input, lo half of vv broadcast)
__device__ __forceinline__ void cmac_rlo(v2f& acc, const u64 g, const v2f vv) {
  asm("v_pk_fma_f32 %0, %1, %2, %0 op_sel:[0,0,0] op_sel_hi:[1,0,1]"
      : "+v"(acc) : "s"(g), "v"(vv));
}
// acc += (gr,gi) * vv.hi
__device__ __forceinline__ void cmac_rhi(v2f& acc, const u64 g, const v2f vv) {
  asm("v_pk_fma_f32 %0, %1, %2, %0 op_sel:[0,1,0] op_sel_hi:[1,1,1]"
      : "+v"(acc) : "s"(g), "v"(vv));
}

// ---------------- K0: partial sum of squares ----------------
__global__ __launch_bounds__(256) void k_sumsq(const float* __restrict__ f,
                                               float* __restrict__ partial) {
  const int t = threadIdx.x;
  const float4* f4 = reinterpret_cast<const float4*>(f) + ((size_t)blockIdx.x << 11);
  float s = 0.f;
#pragma unroll
  for (int i = 0; i < 8; ++i) {
    float4 v = f4[(i << 8) + t];
    s += v.x * v.x + v.y * v.y + v.z * v.z + v.w * v.w;
  }
#pragma unroll
  for (int off = 32; off > 0; off >>= 1) s += __shfl_down(s, off, 64);
  __shared__ float red[4];
  if ((t & 63) == 0) red[t >> 6] = s;
  __syncthreads();
  if (t == 0) partial[blockIdx.x] = (red[0] + red[1]) + (red[2] + red[3]);
}

// ---------------- K0b: finish reduction + gate table ----------------
__global__ __launch_bounds__(256) void k_finish(const float* __restrict__ partial,
                                                const float* __restrict__ gr,
                                                const float* __restrict__ gi,
                                                char* __restrict__ ws) {
  const int t = threadIdx.x;
  float s = 0.f;
#pragma unroll
  for (int i = 0; i < 8; ++i) s += partial[(i << 8) + t];
#pragma unroll
  for (int off = 32; off > 0; off >>= 1) s += __shfl_down(s, off, 64);
  __shared__ float red[4];
  if ((t & 63) == 0) red[t >> 6] = s;
  __syncthreads();
  if (t == 0) *reinterpret_cast<float*>(ws) = 1.0f / ((red[0] + red[1]) + (red[2] + red[3]));
  if (t < 64) {
    const int i = t & 7, j = t >> 3;   // P[j*8+i] = (Gr[i][j], Gi[i][j])
    float2* Pf = reinterpret_cast<float2*>(ws + 64);
    Pf[t] = make_float2(gr[i * 8 + j], gi[i * 8 + j]);
  }
}

// ---------------- K1: axes 3..7 ----------------
// element index e (15b): i3=e[14:12] i4=e[11:9] i5=e[8:6] i6=e[5:3] i7=e[2:0]
template <int STAGE>
__device__ __forceinline__ void stage1_c(__half2* tile, const u64* __restrict__ P,
                                         int eb0, int eb1) {
  const int pb0 = SWZ1(eb0), pb1 = SWZ1(eb1);
  v2f a0[8], a1[8];
#pragma unroll
  for (int i = 0; i < 8; ++i) { a0[i] = mkv(0.f, 0.f); a1[i] = mkv(0.f, 0.f); }
#pragma unroll
  for (int j = 0; j < 8; ++j) {
    const float2 v0f = __half22float2(tile[pb0 ^ tj1(STAGE, j)]);
    const float2 v1f = __half22float2(tile[pb1 ^ tj1(STAGE, j)]);
    const v2f v0 = mkv(v0f.x, v0f.y), v1 = mkv(v1f.x, v1f.y);
#pragma unroll
    for (int i = 0; i < 8; ++i) {
      const u64 g = P[j * 8 + i];
      cmac(a0[i], g, v0);
      cmac(a1[i], g, v1);
    }
  }
#pragma unroll
  for (int i = 0; i < 8; ++i) {
    tile[pb0 ^ tj1(STAGE, i)] = __float22half2_rn(make_float2(a0[i].x, a0[i].y));
    tile[pb1 ^ tj1(STAGE, i)] = __float22half2_rn(make_float2(a1[i].x, a1[i].y));
  }
}

__global__ __launch_bounds__(1024) void k_pass1(const float* __restrict__ f,
                                                const u64* __restrict__ P,
                                                __half2* __restrict__ st) {
  __shared__ __align__(16) __half2 tile[32768];  // 128 KB
  const int t = threadIdx.x;
  const int l = t & 63, w = t >> 6;                 // lane(6b), wave(4b)
  const int l20 = l & 7, l43 = (l >> 3) & 3, l5 = l >> 5;
  const int w20 = w & 7, w3 = w >> 3;
  const int A = (l5 << 2) | l43;                    // 3b {l5,l43}
  const size_t blk = blockIdx.x;

  // fill: coalesced float4 feature loads -> half2(re,0) at swizzled LDS slots.
  {
    const float4* fin = reinterpret_cast<const float4*>(f) + (blk << 13);
    const int d = (l >> 4) & 3;
    const bool b0 = (d & 1) != 0, b1 = (d & 2) != 0;
#pragma unroll
    for (int k = 0; k < 8; ++k) {
      const float4 v = fin[(k << 10) + t];
      const int e0 = (k << 12) | (t << 2);
      const int pblk = SWZ1(e0) & ~3;
      const uint x0 = (uint)__half_as_ushort(__float2half_rn(v.x));
      const uint x1 = (uint)__half_as_ushort(__float2half_rn(v.y));
      const uint x2 = (uint)__half_as_ushort(__float2half_rn(v.z));
      const uint x3 = (uint)__half_as_ushort(__float2half_rn(v.w));
      const uint y0 = b0 ? x1 : x0, y1 = b0 ? x0 : x1;
      const uint y2 = b0 ? x3 : x2, y3 = b0 ? x2 : x3;
      const uint4 W = make_uint4(b1 ? y2 : y0, b1 ? y3 : y1, b1 ? y0 : y2, b1 ? y1 : y3);
      *reinterpret_cast<uint4*>(reinterpret_cast<uint*>(tile) + pblk) = W;
    }
  }
  __syncthreads();

  // stage 7 (axis 7, real input): acc += (gr,gi)*vr, 1 pk_fma per (i,j)
#pragma unroll
  for (int cp = 0; cp < 2; ++cp) {
    const int Wc0 = (w3 << 2) | (cp << 1), Wc1 = Wc0 | 1;
    const int eb0 = (w20 << 12) | (A << 9) | (l20 << 6) | (Wc0 << 3);
    const int eb1 = (w20 << 12) | (A << 9) | (l20 << 6) | (Wc1 << 3);
    const int pb0 = SWZ1(eb0), pb1 = SWZ1(eb1);
    v2f a0[8], a1[8];
#pragma unroll
    for (int i = 0; i < 8; ++i) { a0[i] = mkv(0.f, 0.f); a1[i] = mkv(0.f, 0.f); }
#pragma unroll
    for (int j = 0; j < 8; j += 2) {
      const v2f vv0 = mkv(__half22float2(tile[pb0 ^ j]).x,
                          __half22float2(tile[pb0 ^ (j + 1)]).x);
      const v2f vv1 = mkv(__half22float2(tile[pb1 ^ j]).x,
                          __half22float2(tile[pb1 ^ (j + 1)]).x);
#pragma unroll
      for (int i = 0; i < 8; ++i) {
        const u64 ga = P[j * 8 + i], gb = P[(j + 1) * 8 + i];
        cmac_rlo(a0[i], ga, vv0);
        cmac_rhi(a0[i], gb, vv0);
        cmac_rlo(a1[i], ga, vv1);
        cmac_rhi(a1[i], gb, vv1);
      }
    }
#pragma unroll
    for (int i = 0; i < 8; ++i) {
      tile[pb0 ^ i] = __float22half2_rn(make_float2(a0[i].x, a0[i].y));
      tile[pb1 ^ i] = __float22half2_rn(make_float2(a1[i].x, a1[i].y));
    }
  }
  __syncthreads();

  // stage 6
#pragma unroll
  for (int cp = 0; cp < 2; ++cp) {
    const int Wc0 = (w3 << 2) | (cp << 1), Wc1 = Wc0 | 1;
    stage1_c<6>(tile, P,
                (w20 << 12) | (A << 9) | (Wc0 << 6) | l20,
                (w20 << 12) | (A << 9) | (Wc1 << 6) | l20);
  }
  __syncthreads();
  // stage 5
#pragma unroll
  for (int cp = 0; cp < 2; ++cp) {
    const int Wc0 = (w3 << 2) | (cp << 1), Wc1 = Wc0 | 1;
    stage1_c<5>(tile, P,
                (w20 << 12) | (A << 9) | (Wc0 << 3) | l20,
                (w20 << 12) | (A << 9) | (Wc1 << 3) | l20);
  }
  __syncthreads();
  // stage 4
#pragma unroll
  for (int cp = 0; cp < 2; ++cp) {
    const int Wc0 = (w3 << 2) | (cp << 1), Wc1 = Wc0 | 1;
    stage1_c<4>(tile, P,
                (w20 << 12) | (Wc0 << 6) | (A << 3) | l20,
                (w20 << 12) | (Wc1 << 6) | (A << 3) | l20);
  }
  __syncthreads();

  // stage 3: compute and stream straight to global (coalesced 64-consecutive half2)
#pragma unroll
  for (int cp = 0; cp < 2; ++cp) {
    const int Wc0 = (w3 << 2) | (cp << 1), Wc1 = Wc0 | 1;
    const int eb0 = (w20 << 9) | (Wc0 << 6) | (A << 3) | l20;
    const int eb1 = (w20 << 9) | (Wc1 << 6) | (A << 3) | l20;
    const int pb0 = SWZ1(eb0), pb1 = SWZ1(eb1);
    v2f a0[8], a1[8];
#pragma unroll
    for (int i = 0; i < 8; ++i) { a0[i] = mkv(0.f, 0.f); a1[i] = mkv(0.f, 0.f); }
#pragma unroll
    for (int j = 0; j < 8; ++j) {
      const float2 v0f = __half22float2(tile[pb0 ^ (j << 12)]);
      const float2 v1f = __half22float2(tile[pb1 ^ (j << 12)]);
      const v2f v0 = mkv(v0f.x, v0f.y), v1 = mkv(v1f.x, v1f.y);
#pragma unroll
      for (int i = 0; i < 8; ++i) {
        const u64 g = P[j * 8 + i];
        cmac(a0[i], g, v0);
        cmac(a1[i], g, v1);
      }
    }
    const size_t ob = blk << 15;
#pragma unroll
    for (int i = 0; i < 8; ++i) {
      st[ob + (size_t)((i << 12) | eb0)] = __float22half2_rn(make_float2(a0[i].x, a0[i].y));
      st[ob + (size_t)((i << 12) | eb1)] = __float22half2_rn(make_float2(a1[i].x, a1[i].y));
    }
  }
}

// ---------------- K2: axes 0..2 + |.|^2 ----------------
// element index e (13b): i0=e[12:10] i1=e[9:7] i2=e[6:4] lo=e[3:0]
template <int STAGE>
__device__ __forceinline__ void stage2_c(float2* tile, const u64* __restrict__ P,
                                         int eb0, int eb1) {
  const int pb0 = SWZ2(eb0), pb1 = SWZ2(eb1);
  v2f a0[8], a1[8];
#pragma unroll
  for (int i = 0; i < 8; ++i) { a0[i] = mkv(0.f, 0.f); a1[i] = mkv(0.f, 0.f); }
#pragma unroll
  for (int j = 0; j < 8; ++j) {
    const float2 v0f = tile[pb0 ^ tj2(STAGE, j)];
    const float2 v1f = tile[pb1 ^ tj2(STAGE, j)];
    const v2f v0 = mkv(v0f.x, v0f.y), v1 = mkv(v1f.x, v1f.y);
#pragma unroll
    for (int i = 0; i < 8; ++i) {
      const u64 g = P[j * 8 + i];
      cmac(a0[i], g, v0);
      cmac(a1[i], g, v1);
    }
  }
#pragma unroll
  for (int i = 0; i < 8; ++i) {
    tile[pb0 ^ tj2(STAGE, i)] = make_float2(a0[i].x, a0[i].y);
    tile[pb1 ^ tj2(STAGE, i)] = make_float2(a1[i].x, a1[i].y);
  }
}

__global__ __launch_bounds__(512) void k_pass2(const uint4* gp, const u64* __restrict__ P,
                                               const float* __restrict__ invn2, float* out) {
  __shared__ __align__(16) float2 tile[8192];  // 64 KB
  const int t = threadIdx.x;
  const int l = t & 63, w = t >> 6;            // lane(6b), wave(3b)
  const int l15 = l & 15, l54 = l >> 4;
  const size_t blk = blockIdx.x;               // lows [blk*16, blk*16+16)

  // fill: 64B row (16 half2) per h; pairs of b128 LDS writes
#pragma unroll
  for (int i = 0; i < 4; ++i) {
    const int cidx = (i << 9) + t;
    const int h = cidx >> 2, q = cidx & 3;
    const uint4 raw = gp[(size_t)h * 8192 + (blk << 2) + q];
    const int e0 = (h << 4) | (q << 2);
    const int p0 = SWZ2(e0);
    const float2 f0 = __half22float2(*reinterpret_cast<const __half2*>(&raw.x));
    const float2 f1 = __half22float2(*reinterpret_cast<const __half2*>(&raw.y));
    const float2 f2 = __half22float2(*reinterpret_cast<const __half2*>(&raw.z));
    const float2 f3 = __half22float2(*reinterpret_cast<const __half2*>(&raw.w));
    float4* t4 = reinterpret_cast<float4*>(tile);
    t4[p0 >> 1] = make_float4(f0.x, f0.y, f1.x, f1.y);
    t4[(p0 >> 1) ^ 1] = make_float4(f2.x, f2.y, f3.x, f3.y);
  }
  __syncthreads();

  // stage 2 (axis 2)
  stage2_c<2>(tile, P,
              (w << 10) | (((l54 << 1) | 0) << 7) | l15,
              (w << 10) | (((l54 << 1) | 1) << 7) | l15);
  __syncthreads();
  // stage 1 (axis 1)
  stage2_c<1>(tile, P,
              (w << 10) | (((0 << 2) | l54) << 4) | l15,
              (w << 10) | (((1 << 2) | l54) << 4) | l15);
  __syncthreads();
  // stage 0 (axis 0)
  stage2_c<0>(tile, P,
              (w << 7) | (((0 << 2) | l54) << 4) | l15,
              (w << 7) | (((1 << 2) | l54) << 4) | l15);
  __syncthreads();

  // final: probs, 4 full 64B lines per store instruction
  const float s = invn2[0];
#pragma unroll
  for (int r = 0; r < 16; ++r) {
    const int h = (r << 5) | (w << 2) | l54;
    const float2 a = tile[SWZ2((h << 4) | l15)];
    out[(size_t)h * 32768 + (blk << 4) + l15] = (a.x * a.x + a.y * a.y) * s;
  }
}

extern "C" void kernel_launch(void* const* d_in, const int* in_sizes, int n_in,
                              void* d_out, int out_size, void* d_ws, size_t ws_size,
                              hipStream_t stream) {
  (void)in_sizes; (void)n_in; (void)out_size; (void)ws_size;
  const float* feature = (const float*)d_in[0];
  const float* gr = (const float*)d_in[1];
  const float* gi = (const float*)d_in[2];
  float* out = (float*)d_out;
  char* ws = (char*)d_ws;
  const float* invn2 = (const float*)ws;                           // ws+0
  const u64* P = reinterpret_cast<const u64*>(ws + 64);            // float2[64]

  // partials live in the front of d_out; K1 overwrites d_out afterwards.
  k_sumsq<<<dim3(2048), dim3(256), 0, stream>>>(feature, out);
  k_finish<<<dim3(1), dim3(256), 0, stream>>>(out, gr, gi, ws);
  k_pass1<<<dim3(512), dim3(1024), 0, stream>>>(feature, P, (__half2*)d_out);
  k_pass2<<<dim3(2048), dim3(512), 0, stream>>>((const uint4*)d_out, P, invn2, out);
}

// Round 4
// 71.362 us; speedup vs baseline: 2.9627x; 2.2404x over previous
//
#include <hip/hip_runtime.h>

// probs = |U^{x8} f|^2 / ||f||^2, U = 8x8 complex gate on each of 8 qubit triples.
// MFMA: per 3-qubit axis, D = A*B, A(16x16 f16) = [[Gr,-Gi],[Gi,Gr]], B = 16
// rest-columns of [Xr;Xi], f32 accumulate (v_mfma_f32_16x16x16_f16).
//
// State tile lives in 128KB LDS as halfwords, layout L(s) with byte index
//   [e3(3) | e2(3) | e1(3) | e0(3) | p(1) | k(3) | half] * 2
// k = current axis digit (k-fastest -> B fragment = one ds_read_b64 of 4
// consecutive halves). One UNIFORM stage formula rotates digits k<-e3,
// e0<-output digit, e1<-e0, e2<-e1, e3<-e2 each stage (verified closure).
// All LDS accesses go through SW(): phys = log ^ (((log>>8)&0xF)<<3)
// (bank-minimum verified for every access pattern; involution => bijective).
//
// k_pass1: axes A3..A7 (low 15 bits of global index). 512 blocks x 1024 thr.
//   fill (+ fused ||f||^2 partials -> d_ws), 4 LDS stages, 5th stage streams
//   (re,im) f16 pairs to d_out: chunk layout [A0A1A2 | A3A4A5 | A6 A7 | p]
//   = 256B chunk per (A0A1A2, A3A4A5) -> pass2 block b reads/writes ONLY the
//   byte set {x*131072 + b*256 + [0,256)} => race-free in-place.
// k_pass2: axes A0..A2. 512 blocks x 1024 thr. fill, 2 LDS stages, final
//   stage: probs = (re^2+im^2)/sum -> d_out, 64B-contiguous store runs.

typedef _Float16 f16;
typedef _Float16 f16x4 __attribute__((ext_vector_type(4)));
typedef float f32x4 __attribute__((ext_vector_type(4)));
typedef unsigned int u32;
typedef unsigned short u16;

__device__ __forceinline__ u32 SW(u32 a) { return a ^ (((a >> 8) & 0xFu) << 3); }

__device__ __forceinline__ u32 PK(float x, float y) {
  return __builtin_bit_cast(u32, __builtin_amdgcn_cvt_pkrtz(x, y));
}

// A fragment for v_mfma_f32_16x16x16_f16: lane holds A[row = l&15][k=(l>>4)*4+e].
// A = [[Gr, -Gi], [Gi, Gr]]; rows 0-7 -> re out, 8-15 -> im out; k<8 hits Xr.
__device__ __forceinline__ f16x4 build_A(const float* __restrict__ gr,
                                         const float* __restrict__ gi, int l) {
  const int row = l & 15, kg = l >> 4;
  const int pg = row & 7, rpl = row >> 3, kpl = kg >> 1;
  f16x4 a;
#pragma unroll
  for (int e = 0; e < 4; ++e) {
    const int j = (kg & 1) * 4 + e;
    const float grv = gr[pg * 8 + j], giv = gi[pg * 8 + j];
    const float v = rpl == 0 ? (kpl == 0 ? grv : -giv) : (kpl == 0 ? giv : grv);
    a[e] = (f16)v;
  }
  return a;
}

// One in-LDS gate stage (read all -> barrier -> write all -> barrier).
// Read:  log = j*8192 + w*512 + c*32 + kg*8            (G = j*16 + w)
// Write: log = (w>>2)<<14 | ((w&3)*2+c3)<<11 | (c&7)<<8 | (kg&1)<<7 | p<<4
//              | (g&1)<<16 | (g>>1)<<3 | rr<<5 ; 4 MFMAs (m=j[2:1]) packed.
__device__ __forceinline__ void lds_stage(char* lb, f16x4 A, int w, int l) {
  const int kg = l >> 4, c = l & 15, c3 = c >> 3, p = kg >> 1;
  const u32 rb = (u32)(w * 512 + c * 32 + kg * 8);
  const f32x4 Z = {0.f, 0.f, 0.f, 0.f};
  f32x4 acc[16];
#pragma unroll
  for (int g = 0; g < 4; ++g) {
#pragma unroll
    for (int m = 0; m < 4; ++m) {
      const int j = (g & 1) + m * 2 + (g >> 1) * 8;
      const uint2 bw = *(const uint2*)(lb + SW(rb + (u32)j * 8192u));
      acc[g * 4 + m] = __builtin_amdgcn_mfma_f32_16x16x16f16(
          A, __builtin_bit_cast(f16x4, bw), Z, 0, 0, 0);
    }
  }
  __syncthreads();  // all reads everywhere done -> in-place writes safe
  const u32 wl = (u32)(((w >> 2) << 14) + (((w & 3) * 2 + c3) << 11) +
                       ((c & 7) << 8) + ((kg & 1) << 7) + (p << 4));
#pragma unroll
  for (int g = 0; g < 4; ++g) {
#pragma unroll
    for (int rr = 0; rr < 4; ++rr) {
      const u32 d0 = PK(acc[g * 4 + 0][rr], acc[g * 4 + 1][rr]);
      const u32 d1 = PK(acc[g * 4 + 2][rr], acc[g * 4 + 3][rr]);
      const u32 lg = wl + (u32)(((g & 1) << 16) + ((g >> 1) << 3) + (rr << 5));
      *(uint2*)(lb + SW(lg)) = make_uint2(d0, d1);
    }
  }
  __syncthreads();
}

__global__ __launch_bounds__(1024, 4) void k_pass1(
    const float* __restrict__ f, const float* __restrict__ gr,
    const float* __restrict__ gi, uint4* __restrict__ st,
    float* __restrict__ wsp) {
  __shared__ __align__(16) char lb[131072];
  __shared__ float red[16];
  const int t = threadIdx.x, l = t & 63, w = t >> 6, blk = blockIdx.x;
  const int kg = l >> 4, c = l & 15, c3 = c >> 3, p = kg >> 1;
  const f16x4 A = build_A(gr, gi, l);

  // ---- fill L(0): [A4|A5|A6|A7|p|A3], re = f, im = 0; fused ||f||^2 ----
  float s = 0.f;
  const float4* fin = (const float4*)f + (size_t)blk * 8192;
  const u32 fl = (u32)(((t >> 7) << 14) + (((t >> 4) & 7) << 11) +
                       (((t >> 1) & 7) << 8) + ((t & 1) << 7));
#pragma unroll
  for (int g2 = 0; g2 < 2; ++g2) {
    float4 v0 = fin[(g2 * 4 + 0) * 1024 + t];
    float4 v1 = fin[(g2 * 4 + 1) * 1024 + t];
    float4 v2 = fin[(g2 * 4 + 2) * 1024 + t];
    float4 v3 = fin[(g2 * 4 + 3) * 1024 + t];
    s += v0.x * v0.x + v0.y * v0.y + v0.z * v0.z + v0.w * v0.w;
    s += v1.x * v1.x + v1.y * v1.y + v1.z * v1.z + v1.w * v1.w;
    s += v2.x * v2.x + v2.y * v2.y + v2.z * v2.z + v2.w * v2.w;
    s += v3.x * v3.x + v3.y * v3.y + v3.z * v3.z + v3.w * v3.w;
#pragma unroll
    for (int q = 0; q < 4; ++q) {
      const float a0 = q == 0 ? v0.x : q == 1 ? v0.y : q == 2 ? v0.z : v0.w;
      const float a1 = q == 0 ? v1.x : q == 1 ? v1.y : q == 2 ? v1.z : v1.w;
      const float a2 = q == 0 ? v2.x : q == 1 ? v2.y : q == 2 ? v2.z : v2.w;
      const float a3 = q == 0 ? v3.x : q == 1 ? v3.y : q == 2 ? v3.z : v3.w;
      const u32 lg = fl + (u32)((q << 5) + (g2 << 3));
      *(uint2*)(lb + SW(lg)) = make_uint2(PK(a0, a1), PK(a2, a3));
      *(uint2*)(lb + SW(lg + 16u)) = make_uint2(0u, 0u);  // im plane
    }
  }
#pragma unroll
  for (int off = 32; off; off >>= 1) s += __shfl_down(s, off, 64);
  if (l == 0) red[w] = s;
  __syncthreads();
  if (t == 0) {
    float a = 0.f;
#pragma unroll
    for (int i = 0; i < 16; ++i) a += red[i];
    wsp[blk] = a;
  }

  lds_stage(lb, A, w, l);  // A3
  lds_stage(lb, A, w, l);  // A4
  lds_stage(lb, A, w, l);  // A5
  lds_stage(lb, A, w, l);  // A6

  // ---- stage A7 + writeout to intermediate (chunk layout) ----
  // L(4) = [A3|A4|A5|A6|p|A7]: c = {A5[0], A6}, j = {A3, A4[2]}, w = {A4[1:0], A5[2:1]}
  const u32 rb = (u32)(w * 512 + c * 32 + kg * 8);
  const f32x4 Z = {0.f, 0.f, 0.f, 0.f};
  const size_t ob = (size_t)blk * 8192;  // uint4 units
#pragma unroll
  for (int j = 0; j < 16; ++j) {
    const uint2 bw = *(const uint2*)(lb + SW(rb + (u32)j * 8192u));
    const f32x4 a = __builtin_amdgcn_mfma_f32_16x16x16f16(
        A, __builtin_bit_cast(f16x4, bw), Z, 0, 0, 0);
    const u32 h01 = PK(a[0], a[1]), h23 = PK(a[2], a[3]);
    const u32 q01 = __shfl_xor(h01, 32, 64), q23 = __shfl_xor(h23, 32, 64);
    if (p == 0) {  // partner (p=1) holds im parts
      const int A3 = j >> 1, A4 = (j & 1) * 4 + (w >> 2), A5 = (w & 3) * 2 + c3;
      uint4 vv;
      vv.x = (h01 & 0xffffu) | (q01 << 16);
      vv.y = (h01 >> 16) | (q01 & 0xffff0000u);
      vv.z = (h23 & 0xffffu) | (q23 << 16);
      vv.w = (h23 >> 16) | (q23 & 0xffff0000u);
      st[ob + (u32)(((A3 * 64 + A4 * 8 + A5) << 4) + ((c & 7) << 1) + (kg & 1))] = vv;
    }
  }
}

__global__ __launch_bounds__(1024, 4) void k_pass2(
    const uint4* gp, const float* __restrict__ gr, const float* __restrict__ gi,
    const float* __restrict__ wsp, float* out) {
  __shared__ __align__(16) char lb[131072];
  __shared__ float red[16];
  const int t = threadIdx.x, l = t & 63, w = t >> 6, b = blockIdx.x;
  const int kg = l >> 4, c = l & 15, c3 = c >> 3, p = kg >> 1;
  const f16x4 A = build_A(gr, gi, l);

  // norm partials reduce (deterministic, no atomics)
  float sp = (t < 512) ? wsp[t] : 0.f;
#pragma unroll
  for (int off = 32; off; off >>= 1) sp += __shfl_down(sp, off, 64);
  if (l == 0) red[w] = sp;

  // ---- fill L(0) = [A1|A0|A6|A7|p|A2] from chunk intermediate ----
  const u32 fl = (u32)(((t >> 7) << 14) + (((t >> 1) & 7) << 8) +
                       ((t & 1) << 7) + (((t >> 4) & 7) << 1));
#pragma unroll
  for (int it = 0; it < 8; ++it) {
    const uint4 raw = gp[(size_t)(it * 64 + (t >> 4)) * 8192 + (u32)(b * 16 + (t & 15))];
    const u32 lgb = fl + (u32)(it << 11);
#pragma unroll
    for (int dq = 0; dq < 4; ++dq) {
      const u32 dw = dq == 0 ? raw.x : dq == 1 ? raw.y : dq == 2 ? raw.z : raw.w;
      const u32 lg = lgb + (u32)(dq << 5);
      *(u16*)(lb + SW(lg)) = (u16)(dw & 0xffffu);         // re (p=0)
      *(u16*)(lb + SW(lg + 16u)) = (u16)(dw >> 16);       // im (p=1)
    }
  }
  __syncthreads();
  float inv;
  {
    float a = 0.f;
#pragma unroll
    for (int i = 0; i < 16; ++i) a += red[i];
    inv = 1.0f / a;
  }

  lds_stage(lb, A, w, l);  // A2
  lds_stage(lb, A, w, l);  // A1

  // ---- stage A0 + probs writeout ----
  // L(2) = [A6|A7|A2|A1|p|A0]; custom map: c = {A7, A6[0]}, j = {A2[1:0], A6[2:1]},
  // w = {A1, A2[2]}  ->  64B-contiguous store runs.
  const u32 l3 = (u32)((c3 << 14) + ((c & 7) << 11) + ((w & 7) << 5) + (kg << 3));
  const f32x4 Z = {0.f, 0.f, 0.f, 0.f};
#pragma unroll
  for (int j = 0; j < 16; ++j) {
    const u32 jp = (u32)(((j >> 2) << 15) + ((j & 3) << 8) + ((w >> 3) << 10));
    const uint2 bw = *(const uint2*)(lb + SW(l3 + jp));
    const f32x4 a = __builtin_amdgcn_mfma_f32_16x16x16f16(
        A, __builtin_bit_cast(f16x4, bw), Z, 0, 0, 0);
    const int A1 = w & 7, A2 = (w >> 3) * 4 + (j & 3);
    const int A6 = (j >> 2) * 2 + c3, A7 = c & 7;
    const size_t gb = ((size_t)A1 << 18) + ((size_t)A2 << 15) +
                      (u32)(b * 64 + A6 * 8 + A7);
#pragma unroll
    for (int rr = 0; rr < 4; ++rr) {
      float qv = a[rr] * a[rr];
      qv += __shfl_xor(qv, 32, 64);  // re^2 + im^2 from partner plane
      if ((rr >> 1) == p) {          // p=0 stores rr 0,1; p=1 stores rr 2,3
        out[gb + ((size_t)((kg & 1) * 4 + rr) << 21)] = qv * inv;
      }
    }
  }
}

extern "C" void kernel_launch(void* const* d_in, const int* in_sizes, int n_in,
                              void* d_out, int out_size, void* d_ws,
                              size_t ws_size, hipStream_t stream) {
  (void)in_sizes; (void)n_in; (void)out_size; (void)ws_size;
  const float* f = (const float*)d_in[0];
  const float* gr = (const float*)d_in[1];
  const float* gi = (const float*)d_in[2];
  float* wsp = (float*)d_ws;  // 512 floats

  k_pass1<<<dim3(512), dim3(1024), 0, stream>>>(f, gr, gi, (uint4*)d_out, wsp);
  k_pass2<<<dim3(512), dim3(1024), 0, stream>>>((const uint4*)d_out, gr, gi,
                                                wsp, (float*)d_out);
}